// Round 8
// baseline (103.227 us; speedup 1.0000x reference)
//
#include <hip/hip_runtime.h>

// RoPE with on-the-fly trig, MONOLITHIC launch, 8 floats/thread via
// SPLIT-HALF layout: thread t handles float4-group t and group t + n4/2.
// Every load/store instruction is perfectly contiguous (16 B/lane = 1 KB
// per wave instruction), unlike round 7's 32B-lane-stride pattern which
// doubled cache-line requests per byte. Each wave issues 2 pos + 2 x
// loads (independent) at birth -> 2x bytes-in-flight vs round 6.
// n4/2 = 8,388,608 is a multiple of 32, so both halves share (g&31):
// one pair of hoisted exp2 serves both chunks.
// Compulsory traffic: 514 MB -> 82.4 us floor at 6.29 TB/s copy ceiling.

typedef float f32x4 __attribute__((ext_vector_type(4)));

__global__ __launch_bounds__(256)
void rope_kernel(const float* __restrict__ x,
                 const int* __restrict__ pos,
                 float* __restrict__ out,
                 int half4) {
    int g  = blockIdx.x * 256 + threadIdx.x;  // float4 group in first half
    int g2 = g + half4;                       // matching group in second half
    int p0 = pos[g >> 5];                     // 4 independent loads, issued at birth
    int p1 = pos[g2 >> 5];
    f32x4 v0 = *(reinterpret_cast<const f32x4*>(x) + g);
    f32x4 v1 = *(reinterpret_cast<const f32x4*>(x) + g2);

    const float K = 0.20762051f;              // log2(10000)/64
    const float INV2PI = 0.15915494309189535f;
    int i0 = (g & 31) << 1;                   // same for g and g2 (half4 % 32 == 0)
    float ifr0 = exp2f(-(float)i0 * K) * INV2PI;        // overlaps the loads
    float ifr1 = exp2f(-(float)(i0 + 1) * K) * INV2PI;

    float pf0 = (float)p0, pf1 = (float)p1;
    float a0 = __builtin_amdgcn_fractf(pf0 * ifr0);     // revolutions in [0,1)
    float a1 = __builtin_amdgcn_fractf(pf0 * ifr1);
    float a2 = __builtin_amdgcn_fractf(pf1 * ifr0);
    float a3 = __builtin_amdgcn_fractf(pf1 * ifr1);
    float s0 = __builtin_amdgcn_sinf(a0), c0 = __builtin_amdgcn_cosf(a0);
    float s1 = __builtin_amdgcn_sinf(a1), c1 = __builtin_amdgcn_cosf(a1);
    float s2 = __builtin_amdgcn_sinf(a2), c2 = __builtin_amdgcn_cosf(a2);
    float s3 = __builtin_amdgcn_sinf(a3), c3 = __builtin_amdgcn_cosf(a3);

    f32x4 r0, r1;
    r0.x = c0 * v0.x - s0 * v0.y;  r0.y = s0 * v0.x + c0 * v0.y;
    r0.z = c1 * v0.z - s1 * v0.w;  r0.w = s1 * v0.z + c1 * v0.w;
    r1.x = c2 * v1.x - s2 * v1.y;  r1.y = s2 * v1.x + c2 * v1.y;
    r1.z = c3 * v1.z - s3 * v1.w;  r1.w = s3 * v1.z + c3 * v1.w;

    *(reinterpret_cast<f32x4*>(out) + g)  = r0;
    *(reinterpret_cast<f32x4*>(out) + g2) = r1;
}

extern "C" void kernel_launch(void* const* d_in, const int* in_sizes, int n_in,
                              void* d_out, int out_size, void* d_ws, size_t ws_size,
                              hipStream_t stream) {
    const float* x   = (const float*)d_in[0];
    const int*   pos = (const int*)d_in[3];
    float* out = (float*)d_out;

    int n4 = out_size / 4;                 // 16,777,216 float4 groups
    int half4 = n4 / 2;                    // 8,388,608
    const int block = 256;
    int grid = half4 / block;              // 32768 blocks, exact
    rope_kernel<<<grid, block, 0, stream>>>(x, pos, out, half4);
}

// Round 9
// 99.779 us; speedup vs baseline: 1.0346x; 1.0346x over previous
//
#include <hip/hip_runtime.h>

// RoPE with on-the-fly trig, MONOLITHIC launch, ONE rotation pair (float2,
// 8 B/lane) per thread: 131072 blocks x 256 threads, no loop.
// Rationale: R5/R7/R8 proved bigger per-wave payloads regress; the limiter
// is the serial pos->trig->store chain per wave. Minimal payload halves the
// chain, doubles wave-level parallelism, and each wave covers exactly one
// 128-elem row -> one wave-uniform pos load (cache-line broadcast).
// freq index j = g & 63; inv_freq[j] = 2^(-j*log2(10000)/64).
// Compulsory traffic: 514 MB -> 82.4 us floor at 6.29 TB/s copy ceiling.

typedef float f32x2 __attribute__((ext_vector_type(2)));

__global__ __launch_bounds__(256)
void rope_kernel(const float* __restrict__ x,
                 const int* __restrict__ pos,
                 float* __restrict__ out) {
    int g = blockIdx.x * 256 + threadIdx.x;   // one (even,odd) pair per thread
    int row = g >> 6;                         // 64 pairs per row: 1 row per wave
    int p = pos[row];                         // wave-uniform load, issued at birth
    f32x2 v = *(reinterpret_cast<const f32x2*>(x) + g);

    const float K = 0.20762051f;              // log2(10000)/64
    const float INV2PI = 0.15915494309189535f;
    int j = g & 63;                           // frequency index (= lane)
    float ifr = exp2f(-(float)j * K) * INV2PI;  // overlaps the loads

    float a = __builtin_amdgcn_fractf((float)p * ifr);  // revolutions in [0,1)
    float s = __builtin_amdgcn_sinf(a);
    float c = __builtin_amdgcn_cosf(a);

    f32x2 r;
    r.x = c * v.x - s * v.y;
    r.y = s * v.x + c * v.y;
    *(reinterpret_cast<f32x2*>(out) + g) = r;
}

extern "C" void kernel_launch(void* const* d_in, const int* in_sizes, int n_in,
                              void* d_out, int out_size, void* d_ws, size_t ws_size,
                              hipStream_t stream) {
    const float* x   = (const float*)d_in[0];
    const int*   pos = (const int*)d_in[3];
    float* out = (float*)d_out;

    int n2 = out_size / 2;                 // 33,554,432 float2 pairs
    const int block = 256;
    int grid = n2 / block;                 // 131072 blocks, exact
    rope_kernel<<<grid, block, 0, stream>>>(x, pos, out);
}

// Round 10
// 87.126 us; speedup vs baseline: 1.1848x; 1.1452x over previous
//
#include <hip/hip_runtime.h>

// RoPE with on-the-fly trig, MONOLITHIC launch, one float4 per thread
// (round-6 structure, confirmed optimal payload/launch shape), plus
// nontemporal hints on the two streaming accesses: x is read once, out is
// written once -> neither should allocate in L2 (write-allocate on the
// 256 MB out stream + 256 MB x stream evicts the 2 MB pos array that has
// 32x per-line reuse). pos load stays cached. Single isolated change vs
// round 6.
// Compulsory traffic: 514 MB -> 82.4 us floor at 6.29 TB/s copy ceiling.

typedef float f32x4 __attribute__((ext_vector_type(4)));

__global__ __launch_bounds__(256)
void rope_kernel(const float* __restrict__ x,
                 const int* __restrict__ pos,
                 float* __restrict__ out) {
    int g = blockIdx.x * 256 + threadIdx.x;   // one float4 group per thread
    int row = g >> 5;                         // 32 float4 groups per 128-elem row
    int p = pos[row];                         // cached: 32-lane broadcast, 32x reuse
    const f32x4 v = __builtin_nontemporal_load(reinterpret_cast<const f32x4*>(x) + g);

    const float K = 0.20762051f;              // log2(10000)/64
    const float INV2PI = 0.15915494309189535f;
    int i0 = (g & 31) << 1;                   // frequency index of first pair
    float ifr0 = exp2f(-(float)i0 * K) * INV2PI;        // overlaps the loads
    float ifr1 = exp2f(-(float)(i0 + 1) * K) * INV2PI;

    float pf = (float)p;
    float a0 = __builtin_amdgcn_fractf(pf * ifr0);      // revolutions in [0,1)
    float a1 = __builtin_amdgcn_fractf(pf * ifr1);
    float s0 = __builtin_amdgcn_sinf(a0);
    float c0 = __builtin_amdgcn_cosf(a0);
    float s1 = __builtin_amdgcn_sinf(a1);
    float c1 = __builtin_amdgcn_cosf(a1);

    f32x4 r;
    r.x = c0 * v.x - s0 * v.y;
    r.y = s0 * v.x + c0 * v.y;
    r.z = c1 * v.z - s1 * v.w;
    r.w = s1 * v.z + c1 * v.w;
    __builtin_nontemporal_store(r, reinterpret_cast<f32x4*>(out) + g);
}

extern "C" void kernel_launch(void* const* d_in, const int* in_sizes, int n_in,
                              void* d_out, int out_size, void* d_ws, size_t ws_size,
                              hipStream_t stream) {
    const float* x   = (const float*)d_in[0];
    const int*   pos = (const int*)d_in[3];
    float* out = (float*)d_out;

    int n4 = out_size / 4;                 // 16,777,216 float4 groups
    const int block = 256;
    int grid = n4 / block;                 // 65536 blocks, exact
    rope_kernel<<<grid, block, 0, stream>>>(x, pos, out);
}